// Round 6
// baseline (392.384 us; speedup 1.0000x reference)
//
#include <hip/hip_runtime.h>

// Problem constants
#define B_  2
#define S_  2048
#define D_  1024
#define H_  16
#define HD_ 64
#define M_  (B_*S_)   // 4096

typedef __attribute__((ext_vector_type(8))) short  short8;   // 8 bf16 (4 VGPRs)
typedef __attribute__((ext_vector_type(4))) float  float4v;  // 4 fp32
typedef __attribute__((ext_vector_type(4))) int    int4v;    // 16B
typedef __attribute__((ext_vector_type(4))) unsigned short ushort4v; // 8B

#define QSCALE 0.03125f   // 1/sqrt(D) = 1/32, folded into Q at QKV epilogue

__device__ __forceinline__ unsigned short f_to_bf16bits(float f) {
    unsigned int x = __builtin_bit_cast(unsigned int, f);
    unsigned int lsb = (x >> 16) & 1u;
    x += 0x7fffu + lsb;               // round-to-nearest-even
    return (unsigned short)(x >> 16);
}

// ---------------------------------------------------------------------------
// fp32 -> bf16 bulk convert: X(4M) + Wq,Wk,Wv,Wo (1M each). 8 elems/thread.
// ---------------------------------------------------------------------------
__global__ __launch_bounds__(256) void cvt_bf16(
    const float* __restrict__ X,  const float* __restrict__ Wq,
    const float* __restrict__ Wk, const float* __restrict__ Wv,
    const float* __restrict__ Wo,
    unsigned short* __restrict__ Xb,  unsigned short* __restrict__ Wqb,
    unsigned short* __restrict__ Wkb, unsigned short* __restrict__ Wvb,
    unsigned short* __restrict__ Wob)
{
    const long t = (long)blockIdx.x * 256 + threadIdx.x;
    const long e = t * 8;
    const float* src; unsigned short* dst; long off;
    if      (e < 4194304) { src = X;  dst = Xb;  off = e; }
    else if (e < 5242880) { src = Wq; dst = Wqb; off = e - 4194304; }
    else if (e < 6291456) { src = Wk; dst = Wkb; off = e - 5242880; }
    else if (e < 7340032) { src = Wv; dst = Wvb; off = e - 6291456; }
    else                  { src = Wo; dst = Wob; off = e - 7340032; }
    float4v a = *(const float4v*)&src[off];
    float4v b = *(const float4v*)&src[off + 4];
    int4v o;
    o[0] = (int)f_to_bf16bits(a[0]) | ((int)f_to_bf16bits(a[1]) << 16);
    o[1] = (int)f_to_bf16bits(a[2]) | ((int)f_to_bf16bits(a[3]) << 16);
    o[2] = (int)f_to_bf16bits(b[0]) | ((int)f_to_bf16bits(b[1]) << 16);
    o[3] = (int)f_to_bf16bits(b[2]) | ((int)f_to_bf16bits(b[3]) << 16);
    *(int4v*)&dst[off] = o;
}

// ---------------------------------------------------------------------------
// NT GEMM, BK=64, distance-1 REGISTER prefetch: next tile's global loads
// issue right after the compute barrier, consumed at next iter's ds_write --
// the 32-MFMA compute section hides L2/L3 latency.
// mode 0: Q  out[((b*H+h)*S+s)*HD+hd] * QSCALE
// mode 1: K  same layout, unscaled
// mode 2: Vt out[((b*H+h)*HD+hd)*S+s] -- operands SWAPPED (A=Wv, B=X)
// mode 3: fp32 row-major out[m*D+n]
// ---------------------------------------------------------------------------
__global__ __launch_bounds__(256) void gemm_bt(
    const unsigned short* __restrict__ A,
    const unsigned short* __restrict__ B0,
    const unsigned short* __restrict__ B1,
    const unsigned short* __restrict__ B2,
    void* __restrict__ O0, void* __restrict__ O1, void* __restrict__ O2,
    int mode_base)
{
    const int K = 1024;
    const int z = blockIdx.z;
    const int mode = mode_base + z;
    const unsigned short* Aop;
    const unsigned short* Bop;
    void* Op = (z == 0) ? O0 : (z == 1) ? O1 : O2;
    int m0, n0;
    if (mode == 2) {            // swapped: A=Wv (rows=out-dim), B=X (rows=s)
        Aop = B2; Bop = A;
        m0 = blockIdx.y * 128;
        n0 = blockIdx.x * 128;
    } else {
        Aop = A;
        Bop = (z == 0) ? B0 : (z == 1) ? B1 : B2;
        m0 = blockIdx.x * 128;
        n0 = blockIdx.y * 128;
    }

    __shared__ alignas(16) unsigned short As[128 * 64];   // 16 KB
    __shared__ alignas(16) unsigned short Bs[128 * 64];   // 16 KB

    const int tid  = threadIdx.x;
    const int wv   = tid >> 6;
    const int lane = tid & 63;
    const int wm   = wv >> 1, wn = wv & 1;
    const int q4   = lane >> 4, l15 = lane & 15;

    // staging: wave w rows [w*32, w*32+32), 4 instrs of 8 rows; lane -> row
    // +lane/8, phys chunk8 = lane&7, logical chunk = phys ^ (row&7)
    const unsigned short* gA[4];
    const unsigned short* gB[4];
    int ldsoff[4];
#pragma unroll
    for (int j = 0; j < 4; j++) {
        const int r = wv * 32 + j * 8 + (lane >> 3);
        const int c = (((lane & 7) ^ (r & 7)) * 8);
        gA[j] = Aop + (long)(m0 + r) * K + c;
        gB[j] = Bop + (long)(n0 + r) * K + c;
        ldsoff[j] = (wv * 32 + j * 8) * 64 + lane * 8;   // phys chunk = lane&7
    }

    // fragment offsets: row*64 + ((ks*4+q4)^(row&7))*8 ; row&7 == l15&7
    int aoff[2][4], boff[2][4];
#pragma unroll
    for (int ks = 0; ks < 2; ks++)
#pragma unroll
        for (int t = 0; t < 4; t++) {
            const int swz = (((ks * 4 + q4) ^ (l15 & 7)) * 8);
            aoff[ks][t] = (wm * 64 + t * 16 + l15) * 64 + swz;
            boff[ks][t] = (wn * 64 + t * 16 + l15) * 64 + swz;
        }

    float4v acc[4][4];
#pragma unroll
    for (int i = 0; i < 4; i++)
#pragma unroll
        for (int j = 0; j < 4; j++) acc[i][j] = (float4v)0.0f;

    // prologue: tile 0 into registers
    int4v ar[4], br[4];
#pragma unroll
    for (int j = 0; j < 4; j++) {
        ar[j] = *(const int4v*)gA[j];
        br[j] = *(const int4v*)gB[j];
        gA[j] += 64; gB[j] += 64;
    }

    for (int k0 = 0; k0 < K; k0 += 64) {
        __syncthreads();
#pragma unroll
        for (int j = 0; j < 4; j++) {
            *(int4v*)&As[ldsoff[j]] = ar[j];
            *(int4v*)&Bs[ldsoff[j]] = br[j];
        }
        __syncthreads();

        if (k0 + 64 < K) {
#pragma unroll
            for (int j = 0; j < 4; j++) {
                ar[j] = *(const int4v*)gA[j];
                br[j] = *(const int4v*)gB[j];
                gA[j] += 64; gB[j] += 64;
            }
        }

#pragma unroll
        for (int ks = 0; ks < 2; ks++) {
            short8 afr[4], bfr[4];
#pragma unroll
            for (int mt = 0; mt < 4; mt++) afr[mt] = *(const short8*)&As[aoff[ks][mt]];
#pragma unroll
            for (int nt = 0; nt < 4; nt++) bfr[nt] = *(const short8*)&Bs[boff[ks][nt]];
#pragma unroll
            for (int mt = 0; mt < 4; mt++)
#pragma unroll
                for (int nt = 0; nt < 4; nt++)
                    acc[mt][nt] = __builtin_amdgcn_mfma_f32_16x16x32_bf16(
                        afr[mt], bfr[nt], acc[mt][nt], 0, 0, 0);
        }
    }

    // Epilogue: C/D layout col=lane&15, row=(lane>>4)*4+r
#pragma unroll
    for (int mt = 0; mt < 4; mt++)
#pragma unroll
        for (int nt = 0; nt < 4; nt++)
#pragma unroll
            for (int r = 0; r < 4; r++) {
                const int m = m0 + wm * 64 + mt * 16 + q4 * 4 + r;
                const int n = n0 + wn * 64 + nt * 16 + l15;
                float v = acc[mt][nt][r];
                if (mode == 3) {
                    ((float*)Op)[(long)m * D_ + n] = v;
                } else if (mode == 2) {
                    const long off = (((long)(n >> 11) * H_ + (m >> 6)) * HD_ + (m & 63)) * S_ + (n & 2047);
                    ((unsigned short*)Op)[off] = f_to_bf16bits(v);
                } else {
                    const long off = ((long)((m >> 11) * H_ + (n >> 6)) * S_ + (m & 2047)) * HD_ + (n & 63);
                    if (mode == 0) v *= QSCALE;
                    ((unsigned short*)Op)[off] = f_to_bf16bits(v);
                }
            }
}

// ---------------------------------------------------------------------------
// Flash attention (no online-max; scores bounded, exp can't overflow fp32;
// normalization divides out constants). 2-WAVE WGs: 32 q-rows per WG, each
// wave 16 q-rows; K-blocks of 64. LDS 20.5 KB -> 8 WGs/CU, entire 2048-WG
// grid co-resident. Register prefetch of next K/V tile + mask.
// Grid: x = bh (mask-row sharing in L2), y = q-block.
// ---------------------------------------------------------------------------
__global__ __launch_bounds__(128, 4) void attn(
    const unsigned short* __restrict__ Q,    // [B,H,S,HD], pre-scaled by 1/32
    const unsigned short* __restrict__ Kk,   // [B,H,S,HD]
    const unsigned short* __restrict__ Vt,   // [B,H,HD,S]
    const float* __restrict__ mask,          // [S,S]
    unsigned short* __restrict__ ctx)        // [B,S,D]
{
    __shared__ alignas(16) unsigned short Ks[64 * 64];    // 8 KB
    __shared__ alignas(16) unsigned short Vs[64 * 64];    // 8 KB
    __shared__ alignas(16) unsigned short Ps[2][16 * 64]; // 4 KB

    const int tid  = threadIdx.x;      // 0..127
    const int wv   = tid >> 6;         // 0..1
    const int lane = tid & 63;
    const int q4   = lane >> 4, l15 = lane & 15;
    const int bh   = blockIdx.x;
    const int q0   = blockIdx.y * 32;

    const long head = (long)bh * S_ * HD_;

    const int qrow = q0 + wv * 16 + l15;
    short8 qfr[2];
    qfr[0] = *(const short8*)&Q[head + (long)qrow * HD_ + q4 * 8];
    qfr[1] = *(const short8*)&Q[head + (long)qrow * HD_ + 32 + q4 * 8];

    float l_acc[4];
#pragma unroll
    for (int r = 0; r < 4; r++) l_acc[r] = 0.0f;
    float4v oacc[4];
#pragma unroll
    for (int dt = 0; dt < 4; dt++) oacc[dt] = (float4v)0.0f;

    // staging (128 thr, 4 x 16B each for K and V): load j covers rows
    // j*16 + tid/8; phys chunk = tid&7, logical = phys ^ (row&7)
    const int srow = tid >> 3;         // 0..15
    const int sch  = tid & 7;
    const int lc   = (sch ^ (srow & 7)) * 8;
    const unsigned short* gK[4];
    const unsigned short* gV[4];
    int ldsOff[4];
#pragma unroll
    for (int j = 0; j < 4; j++) {
        const int row = j * 16 + srow;
        gK[j] = Kk + head + (long)row * HD_ + lc;
        gV[j] = Vt + head + (long)row * S_  + lc;
        ldsOff[j] = row * 64 + sch * 8;
    }

    // per-thread mask row bases
    const float* mrow[4];
#pragma unroll
    for (int r = 0; r < 4; r++)
        mrow[r] = mask + (long)(q0 + wv * 16 + q4 * 4 + r) * S_ + l15;

    // prologue: tile 0 + mask iter 0 into registers
    int4v kr[4], vr[4];
#pragma unroll
    for (int j = 0; j < 4; j++) {
        kr[j] = *(const int4v*)gK[j];
        vr[j] = *(const int4v*)gV[j];
    }
    float mv[4][4];
#pragma unroll
    for (int nt = 0; nt < 4; nt++)
#pragma unroll
        for (int r = 0; r < 4; r++) mv[nt][r] = mrow[r][nt * 16];

    const int pswz = (q4 & 1) * 4;
    const int psl3 = l15 >> 3;

    for (int k0 = 0; k0 < S_; k0 += 64) {
        __syncthreads();   // prior iter's LDS reads done
#pragma unroll
        for (int j = 0; j < 4; j++) {
            *(int4v*)&Ks[ldsOff[j]] = kr[j];
            *(int4v*)&Vs[ldsOff[j]] = vr[j];
        }
        __syncthreads();

        // register prefetch of next K/V tile (consumed next iter)
        if (k0 + 64 < S_) {
#pragma unroll
            for (int j = 0; j < 4; j++) {
                kr[j] = *(const int4v*)(gK[j] + (long)(k0 + 64) * HD_);
                vr[j] = *(const int4v*)(gV[j] + (k0 + 64));
            }
        }

        // QK^T
        float4v sfr[4];
#pragma unroll
        for (int nt = 0; nt < 4; nt++) {
            const int row = nt * 16 + l15;
            const int p0 = ((q4       ^ (row & 7)) * 8);
            const int p1 = (((4 + q4) ^ (row & 7)) * 8);
            short8 kb0 = *(const short8*)&Ks[row * 64 + p0];
            short8 kb1 = *(const short8*)&Ks[row * 64 + p1];
            float4v s = (float4v)0.0f;
            s = __builtin_amdgcn_mfma_f32_16x16x32_bf16(qfr[0], kb0, s, 0, 0, 0);
            s = __builtin_amdgcn_mfma_f32_16x16x32_bf16(qfr[1], kb1, s, 0, 0, 0);
            sfr[nt] = s;
        }

        // mask prefetch for next iteration
        float mvn[4][4];
        const int knext = (k0 + 64 < S_) ? k0 + 64 : k0;
#pragma unroll
        for (int nt = 0; nt < 4; nt++)
#pragma unroll
            for (int r = 0; r < 4; r++) mvn[nt][r] = mrow[r][knext + nt * 16];

        // p = exp(dot_scaled + mask/32); per-lane row sums; P -> swizzled LDS
#pragma unroll
        for (int nt = 0; nt < 4; nt++)
#pragma unroll
            for (int r = 0; r < 4; r++) {
                const float p = __expf(fmaf(mv[nt][r], QSCALE, sfr[nt][r]));
                l_acc[r] += p;
                const int c8 = (nt * 2 + psl3) ^ (pswz + r);
                Ps[wv][(q4 * 4 + r) * 64 + c8 * 8 + (l15 & 7)] = f_to_bf16bits(p);
            }

        const int pp0 = ((q4       ^ (l15 & 7)) * 8);
        const int pp1 = (((4 + q4) ^ (l15 & 7)) * 8);
        short8 pf0 = *(const short8*)&Ps[wv][l15 * 64 + pp0];
        short8 pf1 = *(const short8*)&Ps[wv][l15 * 64 + pp1];

        // O += P V
#pragma unroll
        for (int dt = 0; dt < 4; dt++) {
            const int row = dt * 16 + l15;
            const int p0 = ((q4       ^ (row & 7)) * 8);
            const int p1 = (((4 + q4) ^ (row & 7)) * 8);
            short8 vb0 = *(const short8*)&Vs[row * 64 + p0];
            short8 vb1 = *(const short8*)&Vs[row * 64 + p1];
            float4v o = oacc[dt];
            o = __builtin_amdgcn_mfma_f32_16x16x32_bf16(pf0, vb0, o, 0, 0, 0);
            o = __builtin_amdgcn_mfma_f32_16x16x32_bf16(pf1, vb1, o, 0, 0, 0);
            oacc[dt] = o;
        }

#pragma unroll
        for (int nt = 0; nt < 4; nt++)
#pragma unroll
            for (int r = 0; r < 4; r++) mv[nt][r] = mvn[nt][r];
    }

    // single end-of-loop butterfly over the 16 column-lanes
#pragma unroll
    for (int r = 0; r < 4; r++) {
#pragma unroll
        for (int off = 1; off < 16; off <<= 1)
            l_acc[r] += __shfl_xor(l_acc[r], off);
    }

    const int b = bh >> 4, h = bh & 15;
#pragma unroll
    for (int dt = 0; dt < 4; dt++)
#pragma unroll
        for (int r = 0; r < 4; r++) {
            const int qg = q0 + wv * 16 + q4 * 4 + r;
            const int d  = dt * 16 + l15;
            const float v = oacc[dt][r] / l_acc[r];
            ctx[((long)(b * S_ + qg)) * D_ + h * HD_ + d] = f_to_bf16bits(v);
        }
}

extern "C" void kernel_launch(void* const* d_in, const int* in_sizes, int n_in,
                              void* d_out, int out_size, void* d_ws, size_t ws_size,
                              hipStream_t stream) {
    const float* X    = (const float*)d_in[0];
    const float* mask = (const float*)d_in[1];
    const float* Wq   = (const float*)d_in[2];
    const float* Wk   = (const float*)d_in[3];
    const float* Wv   = (const float*)d_in[4];
    const float* Wo   = (const float*)d_in[5];
    float* out        = (float*)d_out;

    unsigned short* ws = (unsigned short*)d_ws;
    unsigned short* qws  = ws;                 // 4M elems each
    unsigned short* kws  = ws + 4194304;
    unsigned short* vtws = ws + 8388608;
    unsigned short* ctx  = ws + 12582912;
    unsigned short* Xb   = ws + 16777216;      // 4M
    unsigned short* Wqb  = ws + 20971520;      // 1M each
    unsigned short* Wkb  = ws + 22020096;
    unsigned short* Wvb  = ws + 23068672;
    unsigned short* Wob  = ws + 24117248;      // end = 48MB

    cvt_bf16<<<dim3(4096), 256, 0, stream>>>(X, Wq, Wk, Wv, Wo, Xb, Wqb, Wkb, Wvb, Wob);
    gemm_bt<<<dim3(32, 8, 3), 256, 0, stream>>>(Xb, Wqb, Wkb, Wvb, qws, kws, vtws, 0);
    attn<<<dim3(32, 64, 1), 128, 0, stream>>>(qws, kws, vtws, mask, ctx);
    gemm_bt<<<dim3(32, 8, 1), 256, 0, stream>>>(ctx, Wob, Wob, Wob, out, out, out, 3);
}

// Round 7
// 235.899 us; speedup vs baseline: 1.6634x; 1.6634x over previous
//
#include <hip/hip_runtime.h>

// Problem constants
#define B_  2
#define S_  2048
#define D_  1024
#define H_  16
#define HD_ 64
#define M_  (B_*S_)   // 4096

typedef __attribute__((ext_vector_type(8))) short  short8;   // 8 bf16 (4 VGPRs)
typedef __attribute__((ext_vector_type(4))) float  float4v;  // 4 fp32
typedef __attribute__((ext_vector_type(4))) int    int4v;    // 16B
typedef __attribute__((ext_vector_type(4))) unsigned short ushort4v; // 8B

// 1/sqrt(D) * log2(e) folded together: softmax uses exp2 (v_exp_f32 native)
#define PSCALE 0.0450843341f   // (1/32) * 1.4426950408889634

__device__ __forceinline__ unsigned short f_to_bf16bits(float f) {
    unsigned int x = __builtin_bit_cast(unsigned int, f);
    unsigned int lsb = (x >> 16) & 1u;
    x += 0x7fffu + lsb;               // round-to-nearest-even
    return (unsigned short)(x >> 16);
}

__device__ __forceinline__ float fast_exp2(float x) {
#if __has_builtin(__builtin_amdgcn_exp2f)
    return __builtin_amdgcn_exp2f(x);
#else
    return exp2f(x);
#endif
}

// ---------------------------------------------------------------------------
// fp32 -> bf16 bulk convert: X(4M) + Wq,Wk,Wv,Wo (1M each). 8 elems/thread.
// ---------------------------------------------------------------------------
__global__ __launch_bounds__(256) void cvt_bf16(
    const float* __restrict__ X,  const float* __restrict__ Wq,
    const float* __restrict__ Wk, const float* __restrict__ Wv,
    const float* __restrict__ Wo,
    unsigned short* __restrict__ Xb,  unsigned short* __restrict__ Wqb,
    unsigned short* __restrict__ Wkb, unsigned short* __restrict__ Wvb,
    unsigned short* __restrict__ Wob)
{
    const long t = (long)blockIdx.x * 256 + threadIdx.x;
    const long e = t * 8;
    const float* src; unsigned short* dst; long off;
    if      (e < 4194304) { src = X;  dst = Xb;  off = e; }
    else if (e < 5242880) { src = Wq; dst = Wqb; off = e - 4194304; }
    else if (e < 6291456) { src = Wk; dst = Wkb; off = e - 5242880; }
    else if (e < 7340032) { src = Wv; dst = Wvb; off = e - 6291456; }
    else                  { src = Wo; dst = Wob; off = e - 7340032; }
    float4v a = *(const float4v*)&src[off];
    float4v b = *(const float4v*)&src[off + 4];
    int4v o;
    o[0] = (int)f_to_bf16bits(a[0]) | ((int)f_to_bf16bits(a[1]) << 16);
    o[1] = (int)f_to_bf16bits(a[2]) | ((int)f_to_bf16bits(a[3]) << 16);
    o[2] = (int)f_to_bf16bits(b[0]) | ((int)f_to_bf16bits(b[1]) << 16);
    o[3] = (int)f_to_bf16bits(b[2]) | ((int)f_to_bf16bits(b[3]) << 16);
    *(int4v*)&dst[off] = o;
}

// ---------------------------------------------------------------------------
// NT GEMM, BK=64, distance-1 register prefetch (next tile's global loads
// issue after the compute barrier, consumed at next iter's ds_write).
// mode 0: Q  out[((b*H+h)*S+s)*HD+hd] * PSCALE  (exp2-folded softmax scale)
// mode 1: K  same layout, unscaled
// mode 2: Vt out[((b*H+h)*HD+hd)*S+s] -- operands SWAPPED (A=Wv, B=X)
// mode 3: fp32 row-major out[m*D+n]
// ---------------------------------------------------------------------------
__global__ __launch_bounds__(256) void gemm_bt(
    const unsigned short* __restrict__ A,
    const unsigned short* __restrict__ B0,
    const unsigned short* __restrict__ B1,
    const unsigned short* __restrict__ B2,
    void* __restrict__ O0, void* __restrict__ O1, void* __restrict__ O2,
    int mode_base)
{
    const int K = 1024;
    const int z = blockIdx.z;
    const int mode = mode_base + z;
    const unsigned short* Aop;
    const unsigned short* Bop;
    void* Op = (z == 0) ? O0 : (z == 1) ? O1 : O2;
    int m0, n0;
    if (mode == 2) {            // swapped: A=Wv (rows=out-dim), B=X (rows=s)
        Aop = B2; Bop = A;
        m0 = blockIdx.y * 128;
        n0 = blockIdx.x * 128;
    } else {
        Aop = A;
        Bop = (z == 0) ? B0 : (z == 1) ? B1 : B2;
        m0 = blockIdx.x * 128;
        n0 = blockIdx.y * 128;
    }

    __shared__ alignas(16) unsigned short As[128 * 64];   // 16 KB
    __shared__ alignas(16) unsigned short Bs[128 * 64];   // 16 KB

    const int tid  = threadIdx.x;
    const int wv   = tid >> 6;
    const int lane = tid & 63;
    const int wm   = wv >> 1, wn = wv & 1;
    const int q4   = lane >> 4, l15 = lane & 15;

    const unsigned short* gA[4];
    const unsigned short* gB[4];
    int ldsoff[4];
#pragma unroll
    for (int j = 0; j < 4; j++) {
        const int r = wv * 32 + j * 8 + (lane >> 3);
        const int c = (((lane & 7) ^ (r & 7)) * 8);
        gA[j] = Aop + (long)(m0 + r) * K + c;
        gB[j] = Bop + (long)(n0 + r) * K + c;
        ldsoff[j] = (wv * 32 + j * 8) * 64 + lane * 8;   // phys chunk = lane&7
    }

    int aoff[2][4], boff[2][4];
#pragma unroll
    for (int ks = 0; ks < 2; ks++)
#pragma unroll
        for (int t = 0; t < 4; t++) {
            const int swz = (((ks * 4 + q4) ^ (l15 & 7)) * 8);
            aoff[ks][t] = (wm * 64 + t * 16 + l15) * 64 + swz;
            boff[ks][t] = (wn * 64 + t * 16 + l15) * 64 + swz;
        }

    float4v acc[4][4];
#pragma unroll
    for (int i = 0; i < 4; i++)
#pragma unroll
        for (int j = 0; j < 4; j++) acc[i][j] = (float4v)0.0f;

    int4v ar[4], br[4];
#pragma unroll
    for (int j = 0; j < 4; j++) {
        ar[j] = *(const int4v*)gA[j];
        br[j] = *(const int4v*)gB[j];
        gA[j] += 64; gB[j] += 64;
    }

    for (int k0 = 0; k0 < K; k0 += 64) {
        __syncthreads();
#pragma unroll
        for (int j = 0; j < 4; j++) {
            *(int4v*)&As[ldsoff[j]] = ar[j];
            *(int4v*)&Bs[ldsoff[j]] = br[j];
        }
        __syncthreads();

        if (k0 + 64 < K) {
#pragma unroll
            for (int j = 0; j < 4; j++) {
                ar[j] = *(const int4v*)gA[j];
                br[j] = *(const int4v*)gB[j];
                gA[j] += 64; gB[j] += 64;
            }
        }

#pragma unroll
        for (int ks = 0; ks < 2; ks++) {
            short8 afr[4], bfr[4];
#pragma unroll
            for (int mt = 0; mt < 4; mt++) afr[mt] = *(const short8*)&As[aoff[ks][mt]];
#pragma unroll
            for (int nt = 0; nt < 4; nt++) bfr[nt] = *(const short8*)&Bs[boff[ks][nt]];
#pragma unroll
            for (int mt = 0; mt < 4; mt++)
#pragma unroll
                for (int nt = 0; nt < 4; nt++)
                    acc[mt][nt] = __builtin_amdgcn_mfma_f32_16x16x32_bf16(
                        afr[mt], bfr[nt], acc[mt][nt], 0, 0, 0);
        }
    }

#pragma unroll
    for (int mt = 0; mt < 4; mt++)
#pragma unroll
        for (int nt = 0; nt < 4; nt++)
#pragma unroll
            for (int r = 0; r < 4; r++) {
                const int m = m0 + wm * 64 + mt * 16 + q4 * 4 + r;
                const int n = n0 + wn * 64 + nt * 16 + l15;
                float v = acc[mt][nt][r];
                if (mode == 3) {
                    ((float*)Op)[(long)m * D_ + n] = v;
                } else if (mode == 2) {
                    const long off = (((long)(n >> 11) * H_ + (m >> 6)) * HD_ + (m & 63)) * S_ + (n & 2047);
                    ((unsigned short*)Op)[off] = f_to_bf16bits(v);
                } else {
                    const long off = ((long)((m >> 11) * H_ + (n >> 6)) * S_ + (m & 2047)) * HD_ + (n & 63);
                    if (mode == 0) v *= PSCALE;
                    ((unsigned short*)Op)[off] = f_to_bf16bits(v);
                }
            }
}

// ---------------------------------------------------------------------------
// Flash attention (no online-max; scores bounded, exp can't overflow fp32;
// normalization divides out constants). R3 structure: 256 thr / 4 waves,
// in-loop global->VGPR->LDS staging (no cross-barrier register state!),
// zero-conflict XOR swizzle, mask register-prefetch, exp2-native softmax.
// Grid: x = bh, y = q-block of 64.
// ---------------------------------------------------------------------------
__global__ __launch_bounds__(256) void attn(
    const unsigned short* __restrict__ Q,    // [B,H,S,HD], pre-scaled by PSCALE
    const unsigned short* __restrict__ Kk,   // [B,H,S,HD]
    const unsigned short* __restrict__ Vt,   // [B,H,HD,S]
    const float* __restrict__ mask,          // [S,S]
    unsigned short* __restrict__ ctx)        // [B,S,D]
{
    __shared__ alignas(16) unsigned short Ks[64 * 64];    // 8 KB
    __shared__ alignas(16) unsigned short Vs[64 * 64];    // 8 KB
    __shared__ alignas(16) unsigned short Ps[4][16 * 64]; // 8 KB

    const int tid  = threadIdx.x;
    const int wv   = tid >> 6;
    const int lane = tid & 63;
    const int q4   = lane >> 4, l15 = lane & 15;
    const int bh   = blockIdx.x;
    const int q0   = blockIdx.y * 64;

    const long head = (long)bh * S_ * HD_;

    const int qrow = q0 + wv * 16 + l15;
    short8 qfr[2];
    qfr[0] = *(const short8*)&Q[head + (long)qrow * HD_ + q4 * 8];
    qfr[1] = *(const short8*)&Q[head + (long)qrow * HD_ + 32 + q4 * 8];

    float l_acc[4];
#pragma unroll
    for (int r = 0; r < 4; r++) l_acc[r] = 0.0f;
    float4v oacc[4];
#pragma unroll
    for (int dt = 0; dt < 4; dt++) oacc[dt] = (float4v)0.0f;

    // staging: thread -> rows tid>>3 and +32, phys chunk tid&7,
    // logical chunk = phys ^ (row&7); row1&7 == row0&7 so same col offset
    const int row0 = tid >> 3, row1 = row0 + 32, sch = tid & 7;
    const int cc   = ((sch ^ (row0 & 7)) * 8);
    const unsigned short* gK0 = Kk + head + (long)row0 * HD_ + cc;
    const unsigned short* gK1 = Kk + head + (long)row1 * HD_ + cc;
    const unsigned short* gV0 = Vt + head + (long)row0 * S_  + cc;
    const unsigned short* gV1 = Vt + head + (long)row1 * S_  + cc;
    const int ldsOff0 = row0 * 64 + sch * 8;   // phys chunk = sch
    const int ldsOff1 = row1 * 64 + sch * 8;

    // per-thread mask row bases
    const float* mrow[4];
#pragma unroll
    for (int r = 0; r < 4; r++)
        mrow[r] = mask + (long)(q0 + wv * 16 + q4 * 4 + r) * S_ + l15;

    // mask for iter 0 into registers
    float mv[4][4];
#pragma unroll
    for (int nt = 0; nt < 4; nt++)
#pragma unroll
        for (int r = 0; r < 4; r++) mv[nt][r] = mrow[r][nt * 16];

    const int pswz = (q4 & 1) * 4;
    const int psl3 = l15 >> 3;

    for (int k0 = 0; k0 < S_; k0 += 64) {
        __syncthreads();   // prior iter's LDS reads done (WAR)
        // in-loop staging: global -> VGPR -> LDS (no cross-barrier reg state)
        *(int4v*)&Ks[ldsOff0] = *(const int4v*)(gK0 + (long)k0 * HD_);
        *(int4v*)&Ks[ldsOff1] = *(const int4v*)(gK1 + (long)k0 * HD_);
        *(int4v*)&Vs[ldsOff0] = *(const int4v*)(gV0 + k0);
        *(int4v*)&Vs[ldsOff1] = *(const int4v*)(gV1 + k0);
        __syncthreads();

        // QK^T
        float4v sfr[4];
#pragma unroll
        for (int nt = 0; nt < 4; nt++) {
            const int row = nt * 16 + l15;
            const int p0 = ((q4       ^ (row & 7)) * 8);
            const int p1 = (((4 + q4) ^ (row & 7)) * 8);
            short8 kb0 = *(const short8*)&Ks[row * 64 + p0];
            short8 kb1 = *(const short8*)&Ks[row * 64 + p1];
            float4v s = (float4v)0.0f;
            s = __builtin_amdgcn_mfma_f32_16x16x32_bf16(qfr[0], kb0, s, 0, 0, 0);
            s = __builtin_amdgcn_mfma_f32_16x16x32_bf16(qfr[1], kb1, s, 0, 0, 0);
            sfr[nt] = s;
        }

        // mask prefetch for next iteration
        float mvn[4][4];
        const int knext = (k0 + 64 < S_) ? k0 + 64 : k0;
#pragma unroll
        for (int nt = 0; nt < 4; nt++)
#pragma unroll
            for (int r = 0; r < 4; r++) mvn[nt][r] = mrow[r][knext + nt * 16];

        // p = 2^(dot_scaled + mask*PSCALE); per-lane row sums; P -> LDS
#pragma unroll
        for (int nt = 0; nt < 4; nt++)
#pragma unroll
            for (int r = 0; r < 4; r++) {
                const float p = fast_exp2(fmaf(mv[nt][r], PSCALE, sfr[nt][r]));
                l_acc[r] += p;
                const int c8 = (nt * 2 + psl3) ^ (pswz + r);
                Ps[wv][(q4 * 4 + r) * 64 + c8 * 8 + (l15 & 7)] = f_to_bf16bits(p);
            }

        const int pp0 = ((q4       ^ (l15 & 7)) * 8);
        const int pp1 = (((4 + q4) ^ (l15 & 7)) * 8);
        short8 pf0 = *(const short8*)&Ps[wv][l15 * 64 + pp0];
        short8 pf1 = *(const short8*)&Ps[wv][l15 * 64 + pp1];

        // O += P V
#pragma unroll
        for (int dt = 0; dt < 4; dt++) {
            const int row = dt * 16 + l15;
            const int p0 = ((q4       ^ (row & 7)) * 8);
            const int p1 = (((4 + q4) ^ (row & 7)) * 8);
            short8 vb0 = *(const short8*)&Vs[row * 64 + p0];
            short8 vb1 = *(const short8*)&Vs[row * 64 + p1];
            float4v o = oacc[dt];
            o = __builtin_amdgcn_mfma_f32_16x16x32_bf16(pf0, vb0, o, 0, 0, 0);
            o = __builtin_amdgcn_mfma_f32_16x16x32_bf16(pf1, vb1, o, 0, 0, 0);
            oacc[dt] = o;
        }

#pragma unroll
        for (int nt = 0; nt < 4; nt++)
#pragma unroll
            for (int r = 0; r < 4; r++) mv[nt][r] = mvn[nt][r];
    }

    // single end-of-loop butterfly over the 16 column-lanes
#pragma unroll
    for (int r = 0; r < 4; r++) {
#pragma unroll
        for (int off = 1; off < 16; off <<= 1)
            l_acc[r] += __shfl_xor(l_acc[r], off);
    }

    const int b = bh >> 4, h = bh & 15;
#pragma unroll
    for (int dt = 0; dt < 4; dt++)
#pragma unroll
        for (int r = 0; r < 4; r++) {
            const int qg = q0 + wv * 16 + q4 * 4 + r;
            const int d  = dt * 16 + l15;
            const float v = oacc[dt][r] / l_acc[r];
            ctx[((long)(b * S_ + qg)) * D_ + h * HD_ + d] = f_to_bf16bits(v);
        }
}

extern "C" void kernel_launch(void* const* d_in, const int* in_sizes, int n_in,
                              void* d_out, int out_size, void* d_ws, size_t ws_size,
                              hipStream_t stream) {
    const float* X    = (const float*)d_in[0];
    const float* mask = (const float*)d_in[1];
    const float* Wq   = (const float*)d_in[2];
    const float* Wk   = (const float*)d_in[3];
    const float* Wv   = (const float*)d_in[4];
    const float* Wo   = (const float*)d_in[5];
    float* out        = (float*)d_out;

    unsigned short* ws = (unsigned short*)d_ws;
    unsigned short* qws  = ws;                 // 4M elems each
    unsigned short* kws  = ws + 4194304;
    unsigned short* vtws = ws + 8388608;
    unsigned short* ctx  = ws + 12582912;
    unsigned short* Xb   = ws + 16777216;      // 4M
    unsigned short* Wqb  = ws + 20971520;      // 1M each
    unsigned short* Wkb  = ws + 22020096;
    unsigned short* Wvb  = ws + 23068672;
    unsigned short* Wob  = ws + 24117248;      // end = 48MB

    cvt_bf16<<<dim3(4096), 256, 0, stream>>>(X, Wq, Wk, Wv, Wo, Xb, Wqb, Wkb, Wvb, Wob);
    gemm_bt<<<dim3(32, 8, 3), 256, 0, stream>>>(Xb, Wqb, Wkb, Wvb, qws, kws, vtws, 0);
    attn<<<dim3(32, 32, 1), 256, 0, stream>>>(qws, kws, vtws, mask, ctx);
    gemm_bt<<<dim3(32, 8, 1), 256, 0, stream>>>(ctx, Wob, Wob, Wob, out, out, out, 3);
}